// Round 2
// baseline (25040.675 us; speedup 1.0000x reference)
//
#include <hip/hip_runtime.h>
#include <math.h>

#define Dm 1024
#define Bm 8
#define Sm 512

typedef short s16x8 __attribute__((ext_vector_type(8)));
typedef float f32x4 __attribute__((ext_vector_type(4)));
typedef unsigned short u16;

__device__ __forceinline__ float bf2f(u16 u) {
  union { float f; unsigned v; } x; x.v = (unsigned)u << 16; return x.f;
}
__device__ __forceinline__ u16 f2bf(float f) {
  union { float f; unsigned v; } x; x.f = f;
  unsigned r = x.v + 0x7FFFu + ((x.v >> 16) & 1u);
  return (u16)(r >> 16);
}
__device__ __forceinline__ float sigm(float x) { return 1.f / (1.f + expf(-x)); }

// ===================== convert f32 inputs -> canonical bf16 + state init =====================
__global__ void k_conv(const float* __restrict__ x, const float* __restrict__ w1,
                       const float* __restrict__ w2, const float* __restrict__ ww,
                       const float* __restrict__ pw,
                       u16* __restrict__ Xb, u16* __restrict__ Wc,
                       float* __restrict__ Hf, u16* __restrict__ Hb,
                       float* __restrict__ sums, unsigned* __restrict__ cnt,
                       unsigned* __restrict__ gen, unsigned* __restrict__ poison)
{
  long gid = (long)blockIdx.x * blockDim.x + threadIdx.x;
  const long N0 = 4194304, N1 = 1048576, N2 = 1048576, N3 = 524288, N4 = 524288;
  const long T = N0 + N1 + N2 + N3 + N4;
  for (long p = gid; p < T; p += (long)gridDim.x * blockDim.x) {
    long q = p;
    if (q < N0) { Xb[q] = f2bf(x[q]); continue; }
    q -= N0;
    if (q < N1) { Wc[q] = f2bf(w1[q]); continue; }
    q -= N1;
    if (q < N2) { Wc[N1 + q] = f2bf(w2[q]); continue; }
    q -= N2;
    if (q < N3) { Wc[N1 + N2 + q] = f2bf(ww[q]); continue; }
    q -= N3;
    Wc[N1 + N2 + N3 + q] = f2bf(pw[q]);
  }
  if (gid < 2 * Bm * Dm) Hf[gid] = 0.f;
  if (gid < 2 * 2 * 2 * Bm * Dm) Hb[gid] = 0;
  if (gid < 16) sums[gid] = 0.f;
  if (gid == 0) { *cnt = 0; *gen = 0; *poison = 0; }
}

// ===================== fused GEMM (reflection / phi) =====================
// MODE 0: T1 = gelu(rmsnorm(A@W^T+b)*nw)          (bf16 out)
// MODE 1: XrefB = Xres + rw*(rmsnorm(A@W^T+b)*nw - Xres), hi/lo planes, seq-major
// MODE 2: sumdst[b] += ||A@W^T+b||_2 per token row (N=512)
template<int MODE>
__global__ __launch_bounds__(512)
void k_gemm(const u16* __restrict__ A, const u16* __restrict__ W,
            const float* __restrict__ bias, const float* __restrict__ nw,
            const u16* __restrict__ XresB, const float* __restrict__ rwp,
            u16* __restrict__ out0, float* __restrict__ sumdst, int Ncols)
{
  __shared__ u16 At[16 * 1024];
  __shared__ float rowsq[16];
  const int tid = threadIdx.x;
  const int lane = tid & 63, wv = tid >> 6;
  const int rlo = lane & 15, khi = lane >> 4;
  const int m0 = blockIdx.x * 16;

  { // stage 16x1024 bf16 A tile into XOR-swizzled LDS
    int row = tid & 15, c = tid >> 4;   // c in [0,32)
    const char* src = (const char*)(A + (long)(m0 + row) * Dm);
    char* dst = (char*)At + row * 2048;
    int sw = (row & 7) << 4;
#pragma unroll
    for (int i = 0; i < 4; ++i) {
      int bo = c * 64 + i * 16;
      s16x8 v = *(const s16x8*)(src + bo);
      *(s16x8*)(dst + (bo ^ sw)) = v;
    }
  }
  __syncthreads();

  const int j0 = wv * 128;
  const bool act = j0 < Ncols;
  f32x4 zero4 = {0.f, 0.f, 0.f, 0.f};
  f32x4 acc[8];
#pragma unroll
  for (int jt = 0; jt < 8; ++jt) acc[jt] = zero4;

  if (act) {
    const u16* wbase = W + (long)(j0 + rlo) * Dm + khi * 8;
    const char* abase = (const char*)At + rlo * 2048;
    const int asw = (rlo & 7) << 4;
#pragma unroll
    for (int ks = 0; ks < 32; ++ks) {
      s16x8 a = *(const s16x8*)(abase + (((ks * 32 + khi * 8) * 2) ^ asw));
#pragma unroll
      for (int jt = 0; jt < 8; ++jt) {
        s16x8 b = *(const s16x8*)(wbase + (long)jt * 16 * Dm + ks * 32);
        acc[jt] = __builtin_amdgcn_mfma_f32_16x16x32_bf16(a, b, acc[jt], 0, 0, 0);
      }
    }
  }

  if (tid < 16) rowsq[tid] = 0.f;
  __syncthreads();

  float vals[8][4];
  if (act) {
    float rs[4] = {0.f, 0.f, 0.f, 0.f};
#pragma unroll
    for (int jt = 0; jt < 8; ++jt) {
      float bj = bias[j0 + jt * 16 + rlo];
#pragma unroll
      for (int r = 0; r < 4; ++r) {
        float v = acc[jt][r] + bj;
        vals[jt][r] = v;
        rs[r] += v * v;
      }
    }
#pragma unroll
    for (int r = 0; r < 4; ++r) {
#pragma unroll
      for (int m = 1; m < 16; m <<= 1) rs[r] += __shfl_xor(rs[r], m, 64);
    }
    if (rlo == 0) {
#pragma unroll
      for (int r = 0; r < 4; ++r) atomicAdd(&rowsq[khi * 4 + r], rs[r]);
    }
  }
  __syncthreads();

  if constexpr (MODE == 2) {
    if (tid < 16) {
      int token = m0 + tid;
      atomicAdd(&sumdst[token >> 9], sqrtf(rowsq[tid]));
    }
    return;
  } else {
    float rw = 0.f;
    if constexpr (MODE == 1) rw = rwp[0];
    if (act) {
#pragma unroll
      for (int jt = 0; jt < 8; ++jt) {
        int col = j0 + jt * 16 + rlo;
        float nwv = nw[col];
#pragma unroll
        for (int r = 0; r < 4; ++r) {
          int row = khi * 4 + r;
          int token = m0 + row;
          float ms = rowsq[row] * (1.f / 1024.f) + 1.1920929e-07f;
          float y = vals[jt][r] * rsqrtf(ms) * nwv;
          if constexpr (MODE == 0) {
            y = 0.5f * y * (1.f + erff(y * 0.7071067811865476f));
            out0[(long)token * Dm + col] = f2bf(y);
          } else {
            float xf = bf2f(XresB[(long)token * Dm + col]);
            float xr = xf + rw * (y - xf);
            u16 hi = f2bf(xr);
            float lo = xr - bf2f(hi);
            int s = token & (Sm - 1), b = token >> 9;
            long base = ((long)s * 16 + b) * Dm + col;   // [s][plane*8+b][col]
            out0[base] = hi;
            out0[base + 8 * Dm] = f2bf(lo);
          }
        }
      }
    }
  }
}

// ===================== grid barrier =====================
#define NWG_REC 128
#define SPIN_CAP 2000000

__device__ __forceinline__ bool gbar(unsigned* cnt, unsigned* gen, unsigned* poison,
                                     unsigned nwg, unsigned* pflag)
{
  __syncthreads();
  if (threadIdx.x == 0) {
    __threadfence();
    if (__hip_atomic_load(poison, __ATOMIC_RELAXED, __HIP_MEMORY_SCOPE_AGENT)) {
      *pflag = 1;
    } else {
      unsigned g = __hip_atomic_load(gen, __ATOMIC_RELAXED, __HIP_MEMORY_SCOPE_AGENT);
      unsigned a = __hip_atomic_fetch_add(cnt, 1u, __ATOMIC_ACQ_REL, __HIP_MEMORY_SCOPE_AGENT);
      if (a == nwg - 1u) {
        __hip_atomic_store(cnt, 0u, __ATOMIC_RELAXED, __HIP_MEMORY_SCOPE_AGENT);
        __hip_atomic_fetch_add(gen, 1u, __ATOMIC_ACQ_REL, __HIP_MEMORY_SCOPE_AGENT);
      } else {
        int spins = 0;
        while (__hip_atomic_load(gen, __ATOMIC_ACQUIRE, __HIP_MEMORY_SCOPE_AGENT) == g) {
          __builtin_amdgcn_s_sleep(1);
          if (++spins > SPIN_CAP) {
            __hip_atomic_store(poison, 1u, __ATOMIC_RELEASE, __HIP_MEMORY_SCOPE_AGENT);
            *pflag = 1;
            break;
          }
        }
      }
    }
    __threadfence();
  }
  __syncthreads();
  return *pflag == 0;
}

// ===================== persistent pipelined GRU (one outer loop) =====================
// 128 WGs x 256 thr. Role = wg>>5: 0=gi0 GEMM(@t), 1=L0 gates(@t-1), 2=gi1 GEMM(@t-2), 3=L1 gates(@t-3).
// Each WG owns 32 hidden cols; weight rows {d,1024+d,2048+d} held as MFMA B-frags in VGPRs
// (converted f32->bf16 once at preload). A operand: 16 rows = [hi(8);lo(8)] bf16 split of the
// f32 activation => ~f32-accurate recurrence at bf16 MFMA cost.
__global__ __launch_bounds__(256, 1)
void k_rec(const float* __restrict__ wih0, const float* __restrict__ whh0,
           const float* __restrict__ bih0, const float* __restrict__ bhh0,
           const float* __restrict__ wih1, const float* __restrict__ whh1,
           const float* __restrict__ bih1, const float* __restrict__ bhh1,
           const u16* __restrict__ XrefB, u16* __restrict__ y0r,
           float* __restrict__ gi0r, float* __restrict__ gi1r,
           u16* __restrict__ Hb, float* __restrict__ Hf,
           u16* __restrict__ Xb, float* __restrict__ outx,
           unsigned* cnt, unsigned* gen, unsigned* poison)
{
  __shared__ u16 hbuf[16 * 1024];
  __shared__ float part[4][3][16][33];
  __shared__ unsigned pflag;

  const int wg = blockIdx.x;
  const int role = wg >> 5;
  const int d0 = (wg & 31) * 32;
  const int tid = threadIdx.x;
  const int lane = tid & 63, q = tid >> 6;
  const int rlo = lane & 15, khi = lane >> 4;

  if (tid == 0) pflag = 0;

  const float* Wsel = (role == 0) ? wih0 : (role == 1) ? whh0 : (role == 2) ? wih1 : whh1;

  // weight fragments: [kstep within wave's K-quarter][gate][jtile], f32 -> bf16 at preload
  s16x8 bfr[8][3][2];
#pragma unroll
  for (int ks = 0; ks < 8; ++ks)
#pragma unroll
    for (int g = 0; g < 3; ++g)
#pragma unroll
      for (int jt = 0; jt < 2; ++jt) {
        int rowj = g * 1024 + d0 + jt * 16 + rlo;
        const float* p = Wsel + (long)rowj * Dm + q * 256 + ks * 32 + khi * 8;
        s16x8 f;
#pragma unroll
        for (int e = 0; e < 8; ++e) f[e] = (short)f2bf(p[e]);
        bfr[ks][g][jt] = f;
      }
  __syncthreads();

  for (int s = 0; s < Sm + 3; ++s) {
    int t = s - role;
    bool on = (t >= 0) && (t < Sm);
    if (on) {
      const u16* asrc =
          (role == 0) ? XrefB + (long)t * 16 * Dm :
          (role == 1) ? Hb + ((s - 1) & 1) * 16384 :
          (role == 2) ? y0r + (long)(t & 3) * 16 * Dm :
                        Hb + 32768 + ((s - 1) & 1) * 16384;
      { // stage 16x1024 bf16 (hi/lo planes) into swizzled LDS
        int row = tid & 15, c = tid >> 4;   // c in [0,16)
        const char* src = (const char*)(asrc + row * Dm);
        char* dst = (char*)hbuf + row * 2048;
        int sw = (row & 7) << 4;
#pragma unroll
        for (int i = 0; i < 8; ++i) {
          int bo = c * 128 + i * 16;
          s16x8 v = *(const s16x8*)(src + bo);
          *(s16x8*)(dst + (bo ^ sw)) = v;
        }
      }
      __syncthreads();

      f32x4 zero4 = {0.f, 0.f, 0.f, 0.f};
      f32x4 acc[3][2];
#pragma unroll
      for (int g = 0; g < 3; ++g) { acc[g][0] = zero4; acc[g][1] = zero4; }
      const char* abase = (const char*)hbuf + rlo * 2048;
      const int asw = (rlo & 7) << 4;
#pragma unroll
      for (int ks = 0; ks < 8; ++ks) {
        s16x8 a = *(const s16x8*)(abase + (((q * 256 + ks * 32 + khi * 8) * 2) ^ asw));
#pragma unroll
        for (int g = 0; g < 3; ++g)
#pragma unroll
          for (int jt = 0; jt < 2; ++jt)
            acc[g][jt] = __builtin_amdgcn_mfma_f32_16x16x32_bf16(a, bfr[ks][g][jt], acc[g][jt], 0, 0, 0);
      }
#pragma unroll
      for (int g = 0; g < 3; ++g)
#pragma unroll
        for (int jt = 0; jt < 2; ++jt)
#pragma unroll
          for (int r = 0; r < 4; ++r)
            part[q][g][khi * 4 + r][jt * 16 + rlo] = acc[g][jt][r];
      __syncthreads();

      { // output phase: one thread per (b, dd)
        int b = tid >> 5, dd = tid & 31, d = d0 + dd;
        float v[3];
#pragma unroll
        for (int g = 0; g < 3; ++g) {
          float sv = 0.f;
#pragma unroll
          for (int qq = 0; qq < 4; ++qq)
            sv += part[qq][g][b][dd] + part[qq][g][8 + b][dd];   // hi + lo rows
          v[g] = sv;
        }
        if (role == 0 || role == 2) {
          const float* bih = (role == 0) ? bih0 : bih1;
          float* ring = ((role == 0) ? gi0r : gi1r) + ((long)(t & 3) * Bm + b) * 3072;
#pragma unroll
          for (int g = 0; g < 3; ++g)
            ring[g * 1024 + d] = v[g] + bih[g * 1024 + d];
        } else {
          const float* bhh = (role == 1) ? bhh0 : bhh1;
          const float* ring = ((role == 1) ? gi0r : gi1r) + ((long)(t & 3) * Bm + b) * 3072;
          float gr = ring[d] + v[0] + bhh[d];
          float gz = ring[1024 + d] + v[1] + bhh[1024 + d];
          float gn = ring[2048 + d];
          float ghn = v[2] + bhh[2048 + d];
          float rr = sigm(gr), zz = sigm(gz);
          float nn = tanhf(gn + rr * ghn);
          int layer = (role == 1) ? 0 : 1;
          float* hfp = Hf + layer * 8192 + b * 1024 + d;
          float hp = *hfp;
          float hn = (1.f - zz) * nn + zz * hp;
          *hfp = hn;
          u16 hi = f2bf(hn);
          u16 lo = f2bf(hn - bf2f(hi));
          u16* hb = Hb + layer * 32768 + (s & 1) * 16384;
          hb[b * 1024 + d] = hi;
          hb[8192 + b * 1024 + d] = lo;
          if (role == 1) {
            u16* yr = y0r + (long)(t & 3) * 16 * Dm;
            yr[b * 1024 + d] = hi;
            yr[8192 + b * 1024 + d] = lo;
          } else {
            long xi = ((long)b * Sm + t) * Dm + d;
            Xb[xi] = hi;
            if (outx) outx[xi] = hn;
          }
        }
      }
    }
    if (!gbar(cnt, gen, poison, NWG_REC, &pflag)) return;
  }
}

// ===================== final phi =====================
__global__ void k_phi(const float* __restrict__ sums, const float* __restrict__ psc,
                      const float* __restrict__ pbi, float* __restrict__ out)
{
  int b = threadIdx.x;
  if (b < 8) {
    float whole = sums[8 + b] * (1.f / 512.f);
    float parts = sums[b] * (1.f / 1024.f);
    float raw = (whole - parts) / (whole + 1e-8f);
    float phi = psc[0] * raw + pbi[0];
    phi = fminf(fmaxf(phi, 0.f), 1.f);
    out[(long)Bm * Sm * Dm + b] = phi;
  }
}

// ===================== host =====================
extern "C" void kernel_launch(void* const* d_in, const int* in_sizes, int n_in,
                              void* d_out, int out_size, void* d_ws, size_t ws_size,
                              hipStream_t stream)
{
  (void)in_sizes; (void)n_in; (void)out_size;
  const float* x    = (const float*)d_in[0];
  const float* b1   = (const float*)d_in[2];
  const float* r1w  = (const float*)d_in[3];
  const float* b2   = (const float*)d_in[5];
  const float* r2w  = (const float*)d_in[6];
  const float* rw   = (const float*)d_in[7];
  const float* wb   = (const float*)d_in[9];
  const float* pb   = (const float*)d_in[11];
  const float* psc  = (const float*)d_in[12];
  const float* pbi  = (const float*)d_in[13];
  const float* wih0 = (const float*)d_in[14];
  const float* whh0 = (const float*)d_in[15];
  const float* bih0 = (const float*)d_in[16];
  const float* bhh0 = (const float*)d_in[17];
  const float* wih1 = (const float*)d_in[18];
  const float* whh1 = (const float*)d_in[19];
  const float* bih1 = (const float*)d_in[20];
  const float* bhh1 = (const float*)d_in[21];
  float* out = (float*)d_out;

  if (ws_size < 45000000) return;

  char* ws = (char*)d_ws;
  size_t off = 0;
  auto alloc = [&](size_t bytes) -> char* {
    char* p = ws + off;
    off += (bytes + 255) & ~(size_t)255;
    return p;
  };
  u16*      Xb    = (u16*)  alloc((size_t)4194304 * 2);
  u16*      T1    = (u16*)  alloc((size_t)4194304 * 2);
  u16*      XrefB = (u16*)  alloc((size_t)2 * 4194304 * 2);  // [S][2*8][1024] hi/lo
  u16*      y0r   = (u16*)  alloc((size_t)4 * 16 * 1024 * 2);
  float*    gi0r  = (float*)alloc((size_t)4 * 8 * 3072 * 4);
  float*    gi1r  = (float*)alloc((size_t)4 * 8 * 3072 * 4);
  u16*      Hb    = (u16*)  alloc((size_t)2 * 2 * 2 * 8192 * 2);
  float*    Hf    = (float*)alloc((size_t)2 * 8192 * 4);
  u16*      Wc    = (u16*)  alloc((size_t)3145728 * 2);      // [w1|w2|ww|pw] bf16
  float*    sums  = (float*)alloc(16 * 4);
  unsigned* cnt   = (unsigned*)alloc(256);
  unsigned* gen   = (unsigned*)alloc(256);
  unsigned* poi   = (unsigned*)alloc(256);

  u16* WcW1 = Wc;
  u16* WcW2 = Wc + 1048576;
  u16* WcWW = Wc + 2097152;
  u16* WcPW = Wc + 2621440;

  k_conv<<<2048, 256, 0, stream>>>((const float*)d_in[0], (const float*)d_in[1],
                                   (const float*)d_in[4], (const float*)d_in[8],
                                   (const float*)d_in[10],
                                   Xb, Wc, Hf, Hb, sums, cnt, gen, poi);
  (void)x;

  for (int loop = 0; loop < 3; ++loop) {
    k_gemm<0><<<256, 512, 0, stream>>>(Xb, WcW1, b1, r1w, nullptr, nullptr, T1, nullptr, 1024);
    k_gemm<1><<<256, 512, 0, stream>>>(T1, WcW2, b2, r2w, Xb, rw, XrefB, nullptr, 1024);
    k_rec<<<NWG_REC, 256, 0, stream>>>(wih0, whh0, bih0, bhh0, wih1, whh1, bih1, bhh1,
                                       XrefB, y0r, gi0r, gi1r, Hb, Hf, Xb,
                                       (loop == 2) ? out : nullptr, cnt, gen, poi);
    if (loop < 2)
      k_gemm<2><<<256, 512, 0, stream>>>(Xb, WcPW, pb, nullptr, nullptr, nullptr, nullptr, sums, 512);
    else
      k_gemm<2><<<256, 512, 0, stream>>>(Xb, WcWW, wb, nullptr, nullptr, nullptr, nullptr, sums + 8, 512);
  }
  k_phi<<<1, 64, 0, stream>>>(sums, psc, pbi, out);
}